// Round 12
// baseline (193.942 us; speedup 1.0000x reference)
//
#include <hip/hip_runtime.h>
#include <math.h>

#define BB 32
#define NN 1024
#define DD 512
#define SS 4
#define RR 64
#define OUTC 256          // SS*RR
#define NT (BB*NN)        // 32768 tokens
#define MT 64             // tokens per fused block (V0/V1/V3)
#define NBLK (NT/MT)      // 512
#define BPB (NN/MT)       // blocks per batch = 16

// LDS A-tile geometry (V0/V1/V3): bf16, row stride 44 u16 (88 B), b64 reads.
#define ASTR 44
#define APLANE (64*ASTR)
#define ABUF (2*APLANE)
// V2 (128-row) geometry
#define APLANE2 (128*ASTR)
#define ABUF2 (2*APLANE2)

typedef float4 f4;
typedef float f32x4 __attribute__((ext_vector_type(4)));
typedef __bf16 bf16x8 __attribute__((ext_vector_type(8)));
typedef unsigned short u16x8 __attribute__((ext_vector_type(8)));

union BF8 { u16x8 u; bf16x8 b; unsigned w[4]; };

__device__ __forceinline__ float hif(float f) {
  return __uint_as_float(__float_as_uint(f) & 0xffff0000u);
}
__device__ __forceinline__ unsigned short topu(float f) {
  return (unsigned short)(__float_as_uint(f) >> 16);
}
__device__ __forceinline__ unsigned pack2(float e0, float e1) {
  return __builtin_amdgcn_perm(__float_as_uint(e1), __float_as_uint(e0), 0x07060302u);
}

#define MFMA(a,b,c) __builtin_amdgcn_mfma_f32_16x16x32_bf16((a),(b),(c),0,0,0)

#define BARRIER_LGKM() do { \
  asm volatile("s_waitcnt lgkmcnt(0)" ::: "memory"); \
  __builtin_amdgcn_s_barrier(); \
} while (0)

// ---------------- prep: sub -> bf16 hi/lo; Gram G_s = S_s S_s^T -> bf16 hi/lo
__global__ __launch_bounds__(256) void prep_kernel(const float* __restrict__ sub,
    unsigned short* __restrict__ subhi, unsigned short* __restrict__ sublo,
    unsigned short* __restrict__ Ghi, unsigned short* __restrict__ Glo) {
  int t = threadIdx.x, blk = blockIdx.x;
  __shared__ __align__(16) float Sl[64][36];
  if (blk < 128) {
    int i = (blk*256 + t)*4;
    f4 v = *(const f4*)&sub[i];
    uint2 hh, ll;
    hh.x = pack2(v.x, v.y); hh.y = pack2(v.z, v.w);
    ll.x = pack2(v.x - hif(v.x), v.y - hif(v.y));
    ll.y = pack2(v.z - hif(v.z), v.w - hif(v.w));
    *(uint2*)&subhi[i] = hh;
    *(uint2*)&sublo[i] = ll;
    return;
  }
  int s = blk - 128;
  int lane = t & 63, w = t >> 6, l15 = lane & 15, l4 = lane >> 4;
  int row = t >> 2, seg = t & 3;
  f4 r0, r1;
  f32x4 acc[4] = {{0,0,0,0},{0,0,0,0},{0,0,0,0},{0,0,0,0}};
  {
    const float* p = &sub[(size_t)(s*RR + row)*DD + seg*8];
    r0 = *(const f4*)p; r1 = *(const f4*)(p+4);
  }
  for (int kc = 0; kc < 16; ++kc) {
    __syncthreads();
    *(f4*)&Sl[row][seg*8]   = r0;
    *(f4*)&Sl[row][seg*8+4] = r1;
    __syncthreads();
    if (kc < 15) {
      const float* p = &sub[(size_t)(s*RR + row)*DD + (kc+1)*32 + seg*8];
      r0 = *(const f4*)p; r1 = *(const f4*)(p+4);
    }
    BF8 ah, al;
    {
      int ra = w*16 + l15;
      f32x4 v0 = *(const f32x4*)&Sl[ra][l4*8];
      f32x4 v1 = *(const f32x4*)&Sl[ra][l4*8+4];
      float ff[8] = {v0[0],v0[1],v0[2],v0[3],v1[0],v1[1],v1[2],v1[3]};
#pragma unroll
      for (int e = 0; e < 8; ++e) { ah.u[e] = topu(ff[e]); al.u[e] = topu(ff[e]-hif(ff[e])); }
    }
#pragma unroll
    for (int j = 0; j < 4; ++j) {
      BF8 bh, bl;
      int rb = j*16 + l15;
      f32x4 v0 = *(const f32x4*)&Sl[rb][l4*8];
      f32x4 v1 = *(const f32x4*)&Sl[rb][l4*8+4];
      float ff[8] = {v0[0],v0[1],v0[2],v0[3],v1[0],v1[1],v1[2],v1[3]};
#pragma unroll
      for (int e = 0; e < 8; ++e) { bh.u[e] = topu(ff[e]); bl.u[e] = topu(ff[e]-hif(ff[e])); }
      acc[j] = MFMA(ah.b, bh.b, acc[j]);
      acc[j] = MFMA(ah.b, bl.b, acc[j]);
      acc[j] = MFMA(al.b, bh.b, acc[j]);
    }
  }
#pragma unroll
  for (int j = 0; j < 4; ++j)
#pragma unroll
    for (int r = 0; r < 4; ++r) {
      int grow = w*16 + l4*4 + r, gcol = j*16 + l15;
      float v = acc[j][r];
      Ghi[((size_t)s*RR + grow)*RR + gcol] = topu(v);
      Glo[((size_t)s*RR + grow)*RR + gcol] = topu(v - hif(v));
    }
}

// ---------------- fused (templated probe set) ------------------------------
// V=0: full pipeline, launch_bounds(512,3)  [REAL outputs]
// V=1: full pipeline, launch_bounds(512,4)  [r8 control -> scratch outputs]
// V=3: skeleton: same 16 barriers + same MFMA count from registers, no LDS
//      ops / no loads in loop (same LDS alloc -> same occupancy) -> scratch
template<int V>
__global__ __launch_bounds__(512, (V==0 ? 3 : 4)) void fused_t(
    const float* __restrict__ x,
    const unsigned short* __restrict__ subhi, const unsigned short* __restrict__ sublo,
    const unsigned short* __restrict__ Ghi, const unsigned short* __restrict__ Glo,
    float inv_denom, int* __restrict__ amax, float* __restrict__ partial,
    float* __restrict__ scratch) {
  __shared__ __align__(16) unsigned short ldsA[4*ABUF];
  __shared__ float ssqarr[64][8];
  __shared__ float prq2[64][4][2];
  __shared__ float Wl[64][4];

  int t = threadIdx.x;
  int lane = t & 63, w = t >> 6;
  int s = w & 3, ch = w >> 2;
  int l15 = lane & 15, l4 = lane >> 4;
  int m0 = blockIdx.x * MT;

  int srow = t >> 3, sseg = t & 7;
  const float* xrow = &x[(size_t)(m0 + srow)*DD + sseg*4];

  f32x4 acc[4][2] = {};
  float ssqp = 0.f;

  auto gload = [&](int c) -> f4 { return *(const f4*)(xrow + c*32); };
  auto cvtwrite = [&](int buf, f4 v) {
    float f0=v.x, f1=v.y, f2=v.z, f3=v.w;
    ssqp += f0*f0 + f1*f1 + f2*f2 + f3*f3;
    uint2 hh, ll;
    hh.x = pack2(f0,f1); hh.y = pack2(f2,f3);
    ll.x = pack2(f0-hif(f0), f1-hif(f1));
    ll.y = pack2(f2-hif(f2), f3-hif(f3));
    unsigned short* p = &ldsA[buf*ABUF + srow*ASTR + sseg*4];
    *(uint2*)p = hh;
    *(uint2*)(p + APLANE) = ll;
  };
  auto loadB = [&](BF8 (&bh)[2], BF8 (&bl)[2], int c) {
#pragma unroll
    for (int nf = 0; nf < 2; ++nf) {
      size_t off = (size_t)(s*64 + ch*32 + nf*16 + l15)*DD + c*32 + l4*8;
      bh[nf].u = *(const u16x8*)&subhi[off];
      bl[nf].u = *(const u16x8*)&sublo[off];
    }
  };
  auto kstep = [&](int buf, BF8 (&bh)[2], BF8 (&bl)[2]) {
#pragma unroll
    for (int mf = 0; mf < 4; ++mf) {
      int row = mf*16 + l15;
      const unsigned short* p = &ldsA[buf*ABUF + row*ASTR + l4*8];
      uint2 h0  = *(const uint2*)p;
      uint2 h1  = *(const uint2*)(p + 4);
      uint2 lo0 = *(const uint2*)(p + APLANE);
      uint2 lo1 = *(const uint2*)(p + APLANE + 4);
      BF8 ah, al;
      ah.w[0]=h0.x;  ah.w[1]=h0.y;  ah.w[2]=h1.x;  ah.w[3]=h1.y;
      al.w[0]=lo0.x; al.w[1]=lo0.y; al.w[2]=lo1.x; al.w[3]=lo1.y;
#pragma unroll
      for (int nf = 0; nf < 2; ++nf) {
        acc[mf][nf] = MFMA(ah.b, bh[nf].b, acc[mf][nf]);
        acc[mf][nf] = MFMA(ah.b, bl[nf].b, acc[mf][nf]);
        acc[mf][nf] = MFMA(al.b, bh[nf].b, acc[mf][nf]);
      }
    }
  };

  if constexpr (V == 3) {
    // skeleton: preload one B pair; 8 intervals of {bar, 48 MFMA x2, bar}
    BF8 bhP[2], blP[2];
    loadB(bhP, blP, 0);
#pragma unroll
    for (int i = 0; i < 8; ++i) {
      BARRIER_LGKM();
#pragma unroll
      for (int rep = 0; rep < 2; ++rep)
#pragma unroll
        for (int mf = 0; mf < 4; ++mf)
#pragma unroll
          for (int nf = 0; nf < 2; ++nf) {
            acc[mf][nf] = MFMA(bhP[nf].b, bhP[nf].b, acc[mf][nf]);
            acc[mf][nf] = MFMA(bhP[nf].b, blP[nf].b, acc[mf][nf]);
            acc[mf][nf] = MFMA(blP[nf].b, bhP[nf].b, acc[mf][nf]);
          }
      BARRIER_LGKM();
    }
    f32x4 sum = {0.f,0.f,0.f,0.f};
#pragma unroll
    for (int mf = 0; mf < 4; ++mf)
#pragma unroll
      for (int nf = 0; nf < 2; ++nf) sum += acc[mf][nf];
    *(f32x4*)&scratch[((size_t)blockIdx.x*512 + t)*4] = sum;
    return;
  } else {
  // ---- full pipeline (V0 / V1) ----
  f4 xrA0 = gload(0), xrA1 = gload(1);
  cvtwrite(0, xrA0); cvtwrite(1, xrA1);
  f4 xrB0 = gload(2), xrB1 = gload(3);
  BARRIER_LGKM();

#pragma unroll
  for (int i = 0; i < 8; ++i) {
    const int cons = (i & 1) * 2;
    const int wr   = cons ^ 2;
    BF8 bhA[2], blA[2], bhB[2], blB[2];
    loadB(bhA, blA, 2*i);
    loadB(bhB, blB, 2*i + 1);
    __builtin_amdgcn_sched_barrier(0);
    if (i < 6) {
      if ((i & 1) == 0) { xrA0 = gload(2*i + 4); xrA1 = gload(2*i + 5); }
      else              { xrB0 = gload(2*i + 4); xrB1 = gload(2*i + 5); }
    }
    __builtin_amdgcn_sched_barrier(0);
    kstep(cons,     bhA, blA);
    kstep(cons + 1, bhB, blB);
    if (i < 7) {
      if ((i & 1) == 0) { cvtwrite(wr, xrB0); cvtwrite(wr + 1, xrB1); }
      else              { cvtwrite(wr, xrA0); cvtwrite(wr + 1, xrA1); }
    }
    BARRIER_LGKM();
  }
  ssqarr[srow][sseg] = ssqp;

  BF8 gh[2][2], gl2[2][2];
#pragma unroll
  for (int kf = 0; kf < 2; ++kf)
#pragma unroll
    for (int nf = 0; nf < 2; ++nf) {
      size_t off = (size_t)(s*RR + (ch*2 + nf)*16 + l15)*RR + kf*32 + l4*8;
      gh[kf][nf].u  = *(const u16x8*)&Ghi[off];
      gl2[kf][nf].u = *(const u16x8*)&Glo[off];
    }
  __syncthreads();

  float* ysc = (float*)&ldsA[0];
#pragma unroll
  for (int h = 0; h < 4; ++h) {
#pragma unroll
    for (int nf = 0; nf < 2; ++nf)
#pragma unroll
      for (int r = 0; r < 4; ++r)
        ysc[s*1088 + (l4*4 + r)*68 + ch*32 + nf*16 + l15] = acc[h][nf][r];
    __syncthreads();
    BF8 yh[2], yl[2];
#pragma unroll
    for (int kf = 0; kf < 2; ++kf) {
      int base = s*1088 + l15*68 + kf*32 + l4*8;
      f32x4 v0 = *(const f32x4*)&ysc[base];
      f32x4 v1 = *(const f32x4*)&ysc[base+4];
      float ff[8] = {v0[0],v0[1],v0[2],v0[3],v1[0],v1[1],v1[2],v1[3]};
#pragma unroll
      for (int e = 0; e < 8; ++e) {
        yh[kf].u[e] = topu(ff[e]);
        yl[kf].u[e] = topu(ff[e] - hif(ff[e]));
      }
    }
    f32x4 z[2] = {};
#pragma unroll
    for (int nf = 0; nf < 2; ++nf)
#pragma unroll
      for (int kf = 0; kf < 2; ++kf) {
        z[nf] = MFMA(yh[kf].b, gh[kf][nf].b,  z[nf]);
        z[nf] = MFMA(yh[kf].b, gl2[kf][nf].b, z[nf]);
        z[nf] = MFMA(yl[kf].b, gh[kf][nf].b,  z[nf]);
      }
#pragma unroll
    for (int r = 0; r < 4; ++r) {
      float qp = z[0][r]*acc[h][0][r] + z[1][r]*acc[h][1][r];
      qp += __shfl_xor(qp, 1); qp += __shfl_xor(qp, 2);
      qp += __shfl_xor(qp, 4); qp += __shfl_xor(qp, 8);
      if (l15 == 0) prq2[h*16 + l4*4 + r][s][ch] = qp;
    }
    __syncthreads();
  }

  if (t < MT) {
    float ss = 0.f;
#pragma unroll
    for (int g = 0; g < 8; ++g) ss += ssqarr[t][g];
    float inv = 1.f / fmaxf(sqrtf(ss), 1e-12f);
    float p0 = sqrtf(fmaxf(prq2[t][0][0] + prq2[t][0][1], 0.f)) * inv * inv_denom;
    float p1 = sqrtf(fmaxf(prq2[t][1][0] + prq2[t][1][1], 0.f)) * inv * inv_denom;
    float p2 = sqrtf(fmaxf(prq2[t][2][0] + prq2[t][2][1], 0.f)) * inv * inv_denom;
    float p3 = sqrtf(fmaxf(prq2[t][3][0] + prq2[t][3][1], 0.f)) * inv * inv_denom;
    float a0=p0, a1=p1, a2=p2, a3=p3, hi, lo;
    hi = fmaxf(a0,a1); lo = fminf(a0,a1); a0=hi; a1=lo;
    hi = fmaxf(a2,a3); lo = fminf(a2,a3); a2=hi; a3=lo;
    hi = fmaxf(a0,a2); lo = fminf(a0,a2); a0=hi; a2=lo;
    hi = fmaxf(a1,a3); lo = fminf(a1,a3); a1=hi; a3=lo;
    hi = fmaxf(a1,a2); lo = fminf(a1,a2); a1=hi; a2=lo;
    float c2 = a0+a1, c3 = c2+a2, c4s = c3+a3;
    int ksup = 1 + (2.f*a1 > c2-1.f) + (3.f*a2 > c3-1.f) + (4.f*a3 > c4s-1.f);
    float csel = (ksup==1) ? a0 : (ksup==2) ? c2 : (ksup==3) ? c3 : c4s;
    float tau = (csel - 1.f) / (float)ksup;
    float q0 = fmaxf(p0-tau, 0.f), q1 = fmaxf(p1-tau, 0.f);
    float q2 = fmaxf(p2-tau, 0.f), q3 = fmaxf(p3-tau, 0.f);
    int arg = 0; float best = q0;
    if (q1 > best) { best = q1; arg = 1; }
    if (q2 > best) { best = q2; arg = 2; }
    if (q3 > best) { best = q3; arg = 3; }
    amax[m0 + t] = arg;
    Wl[t][0] = q0*inv; Wl[t][1] = q1*inv; Wl[t][2] = q2*inv; Wl[t][3] = q3*inv;
  }
  __syncthreads();

  {
    int grp = t >> 7, dcol = t & 127;
    f32x4 a0 = {0,0,0,0};
#pragma unroll 8
    for (int tok = 0; tok < MT; ++tok) {
      f32x4 v = *(const f32x4*)&x[(size_t)(m0 + tok)*DD + dcol*4];
      a0 += v * Wl[tok][grp];
    }
    *(f32x4*)&partial[((size_t)blockIdx.x*4 + grp)*DD + dcol*4] = a0;
  }
  }
}

// ---------------- V2: MT=128, 1024 threads, 16 waves, cap-128 --------------
__global__ __launch_bounds__(1024, 4) void fused_big(
    const float* __restrict__ x,
    const unsigned short* __restrict__ subhi, const unsigned short* __restrict__ sublo,
    float* __restrict__ scratch) {
  __shared__ __align__(16) unsigned short ldsA[2*ABUF2];   // 45056 B

  int t = threadIdx.x;
  int lane = t & 63, w = t >> 6;
  int s = w & 3, ch = (w >> 2) & 1, mh = w >> 3;
  int l15 = lane & 15, l4 = lane >> 4;
  int m0 = blockIdx.x * 128;

  int srow = t >> 3, sseg = t & 7;              // 128 rows x 8 segs
  const float* xrow = &x[(size_t)(m0 + srow)*DD + sseg*4];

  f32x4 acc[4][2] = {};
  float ssqp = 0.f;

  auto gload = [&](int c) -> f4 { return *(const f4*)(xrow + c*32); };
  auto cvtwrite = [&](int buf, f4 v) {
    float f0=v.x, f1=v.y, f2=v.z, f3=v.w;
    ssqp += f0*f0 + f1*f1 + f2*f2 + f3*f3;
    uint2 hh, ll;
    hh.x = pack2(f0,f1); hh.y = pack2(f2,f3);
    ll.x = pack2(f0-hif(f0), f1-hif(f1));
    ll.y = pack2(f2-hif(f2), f3-hif(f3));
    unsigned short* p = &ldsA[buf*ABUF2 + srow*ASTR + sseg*4];
    *(uint2*)p = hh;
    *(uint2*)(p + APLANE2) = ll;
  };
  auto loadB = [&](BF8 (&bh)[2], BF8 (&bl)[2], int c) {
#pragma unroll
    for (int nf = 0; nf < 2; ++nf) {
      size_t off = (size_t)(s*64 + ch*32 + nf*16 + l15)*DD + c*32 + l4*8;
      bh[nf].u = *(const u16x8*)&subhi[off];
      bl[nf].u = *(const u16x8*)&sublo[off];
    }
  };
  auto kstep = [&](int buf, BF8 (&bh)[2], BF8 (&bl)[2]) {
#pragma unroll
    for (int mf = 0; mf < 4; ++mf) {
      int row = mh*64 + mf*16 + l15;
      const unsigned short* p = &ldsA[buf*ABUF2 + row*ASTR + l4*8];
      uint2 h0  = *(const uint2*)p;
      uint2 h1  = *(const uint2*)(p + 4);
      uint2 lo0 = *(const uint2*)(p + APLANE2);
      uint2 lo1 = *(const uint2*)(p + APLANE2 + 4);
      BF8 ah, al;
      ah.w[0]=h0.x;  ah.w[1]=h0.y;  ah.w[2]=h1.x;  ah.w[3]=h1.y;
      al.w[0]=lo0.x; al.w[1]=lo0.y; al.w[2]=lo1.x; al.w[3]=lo1.y;
#pragma unroll
      for (int nf = 0; nf < 2; ++nf) {
        acc[mf][nf] = MFMA(ah.b, bh[nf].b, acc[mf][nf]);
        acc[mf][nf] = MFMA(ah.b, bl[nf].b, acc[mf][nf]);
        acc[mf][nf] = MFMA(al.b, bh[nf].b, acc[mf][nf]);
      }
    }
  };

  f4 xrA0 = gload(0), xrA1 = gload(1);
  cvtwrite(0, xrA0); cvtwrite(1, xrA1);
  f4 xrB0 = gload(2), xrB1 = gload(3);
  BARRIER_LGKM();

#pragma unroll
  for (int i = 0; i < 8; ++i) {
    const int cons = (i & 1) * 2;   // chunk-buffer pair indices (0/1 vs 2/3 via ^2 trick below)
    const int wr   = cons ^ 2;
    BF8 bhA[2], blA[2], bhB[2], blB[2];
    loadB(bhA, blA, 2*i);
    loadB(bhB, blB, 2*i + 1);
    __builtin_amdgcn_sched_barrier(0);
    if (i < 6) {
      if ((i & 1) == 0) { xrA0 = gload(2*i + 4); xrA1 = gload(2*i + 5); }
      else              { xrB0 = gload(2*i + 4); xrB1 = gload(2*i + 5); }
    }
    __builtin_amdgcn_sched_barrier(0);
    // NOTE: only 2 chunk buffers here (buf = chunk & 1): cons maps to {0,1}
    kstep((2*i) & 1,     bhA, blA);
    kstep((2*i + 1) & 1, bhB, blB);
    if (i < 7) {
      if ((i & 1) == 0) { cvtwrite((2*i + 2) & 1, xrB0); cvtwrite((2*i + 3) & 1, xrB1); }
      else              { cvtwrite((2*i + 2) & 1, xrA0); cvtwrite((2*i + 3) & 1, xrA1); }
    }
    BARRIER_LGKM();
    (void)cons; (void)wr;
  }

  f32x4 sum = {ssqp, 0.f, 0.f, 0.f};
#pragma unroll
  for (int mf = 0; mf < 4; ++mf)
#pragma unroll
    for (int nf = 0; nf < 2; ++nf) sum += acc[mf][nf];
  *(f32x4*)&scratch[((size_t)blockIdx.x*1024 + t)*4] = sum;
}

// ---------------- finish: vote (recomputed per slice) + reduce -------------
__global__ __launch_bounds__(256) void finish_kernel(const int* __restrict__ amax,
    const float* __restrict__ partial, const int* __restrict__ mask,
    float* __restrict__ out) {
  __shared__ int cnt[4];
  __shared__ int vsh;
  int bb = blockIdx.x >> 3, slice = blockIdx.x & 7;
  int t = threadIdx.x;
  if (t < 4) cnt[t] = 0;
  __syncthreads();
  int m = mask[bb];
  int c0=0, c1=0, c2=0, c3=0;
  for (int n = t; n < NN; n += 256) {
    if (n < m) {
      int a = amax[bb*NN + n];
      c0 += (a==0); c1 += (a==1); c2 += (a==2); c3 += (a==3);
    }
  }
  atomicAdd(&cnt[0], c0); atomicAdd(&cnt[1], c1);
  atomicAdd(&cnt[2], c2); atomicAdd(&cnt[3], c3);
  __syncthreads();
  if (t == 0) {
    int arg = 0, best = cnt[0];
    if (cnt[1] > best) { best = cnt[1]; arg = 1; }
    if (cnt[2] > best) { best = cnt[2]; arg = 2; }
    if (cnt[3] > best) { best = cnt[3]; arg = 3; }
    vsh = arg;
  }
  __syncthreads();
  int v = vsh;
  if (t < 64) {
    int d = slice*64 + t;
    float f = 0.f;
#pragma unroll
    for (int c = 0; c < BPB; ++c)
      f += partial[(((size_t)(bb*BPB + c))*4 + v)*DD + d];
    out[bb*DD + d] = f;
  }
}

extern "C" void kernel_launch(void* const* d_in, const int* in_sizes, int n_in,
                              void* d_out, int out_size, void* d_ws, size_t ws_size,
                              hipStream_t stream) {
  const float* x    = (const float*)d_in[0];
  const int*   mask = (const int*)d_in[1];
  const float* sub  = (const float*)d_in[2];
  float* out = (float*)d_out;

  float* partial = (float*)d_ws;                           // 4 MB (real)
  int*   amax    = (int*)(partial + (size_t)NBLK*4*DD);    // 128 KB (real)
  unsigned short* subhi = (unsigned short*)(amax + NT);
  unsigned short* sublo = subhi + OUTC*DD;
  unsigned short* Ghi   = sublo + OUTC*DD;
  unsigned short* Glo   = Ghi + SS*RR*RR;
  float* partialS = (float*)(Glo + SS*RR*RR);              // 4 MB (probe)
  int*   amaxS    = (int*)(partialS + (size_t)NBLK*4*DD);  // 128 KB (probe)
  float* scratch  = (float*)(amaxS + NT);                  // 4 MB (probe sinks)

  double scale = 1.718 * exp(-((double)BB) / 30000.0) - 0.718;
  float inv_denom = (float)(1.0 / ((double)DD * scale));

  prep_kernel<<<128 + SS, 256, 0, stream>>>(sub, subhi, sublo, Ghi, Glo);
  // V0: real outputs, relaxed launch bounds
  fused_t<0><<<NBLK, 512, 0, stream>>>(x, subhi, sublo, Ghi, Glo, inv_denom, amax, partial, scratch);
  // V1: r8 control
  fused_t<1><<<NBLK, 512, 0, stream>>>(x, subhi, sublo, Ghi, Glo, inv_denom, amaxS, partialS, scratch);
  // V2: 128-token / 1024-thread tile
  fused_big<<<NT/128, 1024, 0, stream>>>(x, subhi, sublo, scratch);
  // V3: barrier+MFMA skeleton
  fused_t<3><<<NBLK, 512, 0, stream>>>(x, subhi, sublo, Ghi, Glo, inv_denom, amaxS, partialS, scratch);
  finish_kernel<<<BB*8, 256, 0, stream>>>(amax, partial, mask, out);
}

// Round 13
// 81.615 us; speedup vs baseline: 2.3763x; 2.3763x over previous
//
#include <hip/hip_runtime.h>
#include <math.h>

#define BB 32
#define NN 1024
#define DD 512
#define SS 4
#define RR 64
#define OUTC 256          // SS*RR
#define NT (BB*NN)        // 32768 tokens
#define MT 64             // tokens per fused block
#define NBLK (NT/MT)      // 512
#define BPB (NN/MT)       // blocks per batch = 16

// LDS A-tile geometry: bf16, row stride 44 u16 (88 B); 8B-aligned b64 reads.
#define ASTR 44
#define APLANE (64*ASTR)       // u16 per plane (hi or lo)
#define ABUF (2*APLANE)        // u16 per chunk buffer (hi+lo)

typedef float4 f4;
typedef float f32x4 __attribute__((ext_vector_type(4)));
typedef __bf16 bf16x8 __attribute__((ext_vector_type(8)));
typedef unsigned short u16x8 __attribute__((ext_vector_type(8)));

union BF8 { u16x8 u; bf16x8 b; unsigned w[4]; };

__device__ __forceinline__ float hif(float f) {
  return __uint_as_float(__float_as_uint(f) & 0xffff0000u);
}
__device__ __forceinline__ unsigned short topu(float f) {
  return (unsigned short)(__float_as_uint(f) >> 16);
}
// identity-order pack: (bf16(e0), bf16(e1)) -> u32 (e0 in low half)
__device__ __forceinline__ unsigned pack2(float e0, float e1) {
  return __builtin_amdgcn_perm(__float_as_uint(e1), __float_as_uint(e0), 0x07060302u);
}

#define MFMA(a,b,c) __builtin_amdgcn_mfma_f32_16x16x32_bf16((a),(b),(c),0,0,0)

// lgkm-only barrier: LDS ops visible across waves; vmcnt loads survive.
#define BARRIER_LGKM() do { \
  asm volatile("s_waitcnt lgkmcnt(0)" ::: "memory"); \
  __builtin_amdgcn_s_barrier(); \
} while (0)

// ---------------- prep: sub -> bf16 hi/lo; Gram G_s = S_s S_s^T -> bf16 hi/lo
__global__ __launch_bounds__(256) void prep_kernel(const float* __restrict__ sub,
    unsigned short* __restrict__ subhi, unsigned short* __restrict__ sublo,
    unsigned short* __restrict__ Ghi, unsigned short* __restrict__ Glo) {
  int t = threadIdx.x, blk = blockIdx.x;
  __shared__ __align__(16) float Sl[64][36];
  if (blk < 128) {
    int i = (blk*256 + t)*4;
    f4 v = *(const f4*)&sub[i];
    uint2 hh, ll;
    hh.x = pack2(v.x, v.y); hh.y = pack2(v.z, v.w);
    ll.x = pack2(v.x - hif(v.x), v.y - hif(v.y));
    ll.y = pack2(v.z - hif(v.z), v.w - hif(v.w));
    *(uint2*)&subhi[i] = hh;
    *(uint2*)&sublo[i] = ll;
    return;
  }
  int s = blk - 128;
  int lane = t & 63, w = t >> 6, l15 = lane & 15, l4 = lane >> 4;
  int row = t >> 2, seg = t & 3;
  f4 r0, r1;
  f32x4 acc[4] = {{0,0,0,0},{0,0,0,0},{0,0,0,0},{0,0,0,0}};
  {
    const float* p = &sub[(size_t)(s*RR + row)*DD + seg*8];
    r0 = *(const f4*)p; r1 = *(const f4*)(p+4);
  }
#pragma unroll 1
  for (int kc = 0; kc < 16; ++kc) {
    __syncthreads();
    *(f4*)&Sl[row][seg*8]   = r0;
    *(f4*)&Sl[row][seg*8+4] = r1;
    __syncthreads();
    if (kc < 15) {
      const float* p = &sub[(size_t)(s*RR + row)*DD + (kc+1)*32 + seg*8];
      r0 = *(const f4*)p; r1 = *(const f4*)(p+4);
    }
    BF8 ah, al;
    {
      int ra = w*16 + l15;
      f32x4 v0 = *(const f32x4*)&Sl[ra][l4*8];
      f32x4 v1 = *(const f32x4*)&Sl[ra][l4*8+4];
      float ff[8] = {v0[0],v0[1],v0[2],v0[3],v1[0],v1[1],v1[2],v1[3]};
#pragma unroll
      for (int e = 0; e < 8; ++e) { ah.u[e] = topu(ff[e]); al.u[e] = topu(ff[e]-hif(ff[e])); }
    }
#pragma unroll
    for (int j = 0; j < 4; ++j) {
      BF8 bh, bl;
      int rb = j*16 + l15;
      f32x4 v0 = *(const f32x4*)&Sl[rb][l4*8];
      f32x4 v1 = *(const f32x4*)&Sl[rb][l4*8+4];
      float ff[8] = {v0[0],v0[1],v0[2],v0[3],v1[0],v1[1],v1[2],v1[3]};
#pragma unroll
      for (int e = 0; e < 8; ++e) { bh.u[e] = topu(ff[e]); bl.u[e] = topu(ff[e]-hif(ff[e])); }
      acc[j] = MFMA(ah.b, bh.b, acc[j]);
      acc[j] = MFMA(ah.b, bl.b, acc[j]);
      acc[j] = MFMA(al.b, bh.b, acc[j]);
    }
  }
#pragma unroll
  for (int j = 0; j < 4; ++j)
#pragma unroll
    for (int r = 0; r < 4; ++r) {
      int grow = w*16 + l4*4 + r, gcol = j*16 + l15;
      float v = acc[j][r];
      Ghi[((size_t)s*RR + grow)*RR + gcol] = topu(v);
      Glo[((size_t)s*RR + grow)*RR + gcol] = topu(v - hif(v));
    }
}

// ---------------- fused: r8 structure with a ROLLED main loop --------------
// 8 waves (512 thr): wave w -> subspace s=w&3, col-half ch=w>>2.
// Main loop: 8 intervals (2 k-chunks each), #pragma unroll 1 -> ~1.3 KB body.
__global__ __launch_bounds__(512, 4) void fused_kernel(
    const float* __restrict__ x,
    const unsigned short* __restrict__ subhi, const unsigned short* __restrict__ sublo,
    const unsigned short* __restrict__ Ghi, const unsigned short* __restrict__ Glo,
    float inv_denom, int* __restrict__ amax, float* __restrict__ partial) {
  __shared__ __align__(16) unsigned short ldsA[4*ABUF];  // 45056 B; reused as y scratch
  __shared__ float ssqarr[64][8];
  __shared__ float prq2[64][4][2];
  __shared__ float Wl[64][4];

  int t = threadIdx.x;
  int lane = t & 63, w = t >> 6;
  int s = w & 3, ch = w >> 2;
  int l15 = lane & 15, l4 = lane >> 4;
  int m0 = blockIdx.x * MT;

  int srow = t >> 3, sseg = t & 7;
  const float* xrow = &x[(size_t)(m0 + srow)*DD + sseg*4];

  f32x4 acc[4][2] = {};
  float ssqp = 0.f;

  auto gload = [&](int c) -> f4 { return *(const f4*)(xrow + c*32); };
  auto cvtwrite = [&](int buf, f4 v) {
    float f0=v.x, f1=v.y, f2=v.z, f3=v.w;
    ssqp += f0*f0 + f1*f1 + f2*f2 + f3*f3;
    uint2 hh, ll;
    hh.x = pack2(f0,f1); hh.y = pack2(f2,f3);
    ll.x = pack2(f0-hif(f0), f1-hif(f1));
    ll.y = pack2(f2-hif(f2), f3-hif(f3));
    unsigned short* p = &ldsA[buf*ABUF + srow*ASTR + sseg*4];
    *(uint2*)p = hh;
    *(uint2*)(p + APLANE) = ll;
  };
  auto loadB = [&](BF8 (&bh)[2], BF8 (&bl)[2], int c) {
#pragma unroll
    for (int nf = 0; nf < 2; ++nf) {
      size_t off = (size_t)(s*64 + ch*32 + nf*16 + l15)*DD + c*32 + l4*8;
      bh[nf].u = *(const u16x8*)&subhi[off];
      bl[nf].u = *(const u16x8*)&sublo[off];
    }
  };
  auto kstep = [&](int buf, BF8 (&bh)[2], BF8 (&bl)[2]) {
#pragma unroll
    for (int mf = 0; mf < 4; ++mf) {
      int row = mf*16 + l15;
      const unsigned short* p = &ldsA[buf*ABUF + row*ASTR + l4*8];
      uint2 h0  = *(const uint2*)p;
      uint2 h1  = *(const uint2*)(p + 4);
      uint2 lo0 = *(const uint2*)(p + APLANE);
      uint2 lo1 = *(const uint2*)(p + APLANE + 4);
      BF8 ah, al;
      ah.w[0]=h0.x;  ah.w[1]=h0.y;  ah.w[2]=h1.x;  ah.w[3]=h1.y;
      al.w[0]=lo0.x; al.w[1]=lo0.y; al.w[2]=lo1.x; al.w[3]=lo1.y;
#pragma unroll
      for (int nf = 0; nf < 2; ++nf) {
        acc[mf][nf] = MFMA(ah.b, bh[nf].b, acc[mf][nf]);
        acc[mf][nf] = MFMA(ah.b, bl[nf].b, acc[mf][nf]);
        acc[mf][nf] = MFMA(al.b, bh[nf].b, acc[mf][nf]);
      }
    }
  };

  // prologue: chunks 0,1 -> LDS buffers 0,1; chunks 2,3 -> q regs
  {
    f4 c0v = gload(0), c1v = gload(1);
    cvtwrite(0, c0v); cvtwrite(1, c1v);
  }
  f4 q0 = gload(2), q1 = gload(3);
  BARRIER_LGKM();

#pragma unroll 1
  for (int i = 0; i < 8; ++i) {
    const int cons = (i & 1) * 2;        // buffers consumed: chunks 2i, 2i+1
    const int wr   = cons ^ 2;           // buffers written: chunks 2i+2, 2i+3
    BF8 bhA[2], blA[2], bhB[2], blB[2];
    loadB(bhA, blA, 2*i);
    loadB(bhB, blB, 2*i + 1);
    __builtin_amdgcn_sched_barrier(0);   // pin: B loads issue first
    f4 p0, p1;
    if (i < 6) { p0 = gload(2*i + 4); p1 = gload(2*i + 5); }
    __builtin_amdgcn_sched_barrier(0);   // pin: x loads newest before compute
    kstep(cons,     bhA, blA);
    kstep(cons + 1, bhB, blB);
    if (i < 7) { cvtwrite(wr, q0); cvtwrite(wr + 1, q1); }
    BARRIER_LGKM();
    if (i < 6) { q0 = p0; q1 = p1; }
  }
  ssqarr[srow][sseg] = ssqp;

  // G fragments (L2-resident); identity-order elements match Ghi scalar layout
  BF8 gh[2][2], gl2[2][2];
#pragma unroll
  for (int kf = 0; kf < 2; ++kf)
#pragma unroll
    for (int nf = 0; nf < 2; ++nf) {
      size_t off = (size_t)(s*RR + (ch*2 + nf)*16 + l15)*RR + kf*32 + l4*8;
      gh[kf][nf].u  = *(const u16x8*)&Ghi[off];
      gl2[kf][nf].u = *(const u16x8*)&Glo[off];
    }
  __syncthreads();   // full drain; stage area becomes y scratch

  float* ysc = (float*)&ldsA[0];
#pragma unroll
  for (int h = 0; h < 4; ++h) {
#pragma unroll
    for (int nf = 0; nf < 2; ++nf)
#pragma unroll
      for (int r = 0; r < 4; ++r)
        ysc[s*1088 + (l4*4 + r)*68 + ch*32 + nf*16 + l15] = acc[h][nf][r];
    __syncthreads();                // ysc[s] complete (both halves)
    BF8 yh[2], yl[2];
#pragma unroll
    for (int kf = 0; kf < 2; ++kf) {
      int base = s*1088 + l15*68 + kf*32 + l4*8;
      f32x4 v0 = *(const f32x4*)&ysc[base];
      f32x4 v1 = *(const f32x4*)&ysc[base+4];
      float ff[8] = {v0[0],v0[1],v0[2],v0[3],v1[0],v1[1],v1[2],v1[3]};
#pragma unroll
      for (int e = 0; e < 8; ++e) {
        yh[kf].u[e] = topu(ff[e]);
        yl[kf].u[e] = topu(ff[e] - hif(ff[e]));
      }
    }
    f32x4 z[2] = {};
#pragma unroll
    for (int nf = 0; nf < 2; ++nf)
#pragma unroll
      for (int kf = 0; kf < 2; ++kf) {
        z[nf] = MFMA(yh[kf].b, gh[kf][nf].b,  z[nf]);
        z[nf] = MFMA(yh[kf].b, gl2[kf][nf].b, z[nf]);
        z[nf] = MFMA(yl[kf].b, gh[kf][nf].b,  z[nf]);
      }
#pragma unroll
    for (int r = 0; r < 4; ++r) {
      float qp = z[0][r]*acc[h][0][r] + z[1][r]*acc[h][1][r];
      qp += __shfl_xor(qp, 1); qp += __shfl_xor(qp, 2);
      qp += __shfl_xor(qp, 4); qp += __shfl_xor(qp, 8);
      if (l15 == 0) prq2[h*16 + l4*4 + r][s][ch] = qp;
    }
    __syncthreads();                // readers done before next h overwrites
  }

  if (t < MT) {
    float ss = 0.f;
#pragma unroll
    for (int g = 0; g < 8; ++g) ss += ssqarr[t][g];
    float inv = 1.f / fmaxf(sqrtf(ss), 1e-12f);
    float p0 = sqrtf(fmaxf(prq2[t][0][0] + prq2[t][0][1], 0.f)) * inv * inv_denom;
    float p1 = sqrtf(fmaxf(prq2[t][1][0] + prq2[t][1][1], 0.f)) * inv * inv_denom;
    float p2 = sqrtf(fmaxf(prq2[t][2][0] + prq2[t][2][1], 0.f)) * inv * inv_denom;
    float p3 = sqrtf(fmaxf(prq2[t][3][0] + prq2[t][3][1], 0.f)) * inv * inv_denom;
    float a0=p0, a1=p1, a2=p2, a3=p3, hi, lo;
    hi = fmaxf(a0,a1); lo = fminf(a0,a1); a0=hi; a1=lo;
    hi = fmaxf(a2,a3); lo = fminf(a2,a3); a2=hi; a3=lo;
    hi = fmaxf(a0,a2); lo = fminf(a0,a2); a0=hi; a2=lo;
    hi = fmaxf(a1,a3); lo = fminf(a1,a3); a1=hi; a3=lo;
    hi = fmaxf(a1,a2); lo = fminf(a1,a2); a1=hi; a2=lo;
    float c2 = a0+a1, c3 = c2+a2, c4s = c3+a3;
    int ksup = 1 + (2.f*a1 > c2-1.f) + (3.f*a2 > c3-1.f) + (4.f*a3 > c4s-1.f);
    float csel = (ksup==1) ? a0 : (ksup==2) ? c2 : (ksup==3) ? c3 : c4s;
    float tau = (csel - 1.f) / (float)ksup;
    float q0s = fmaxf(p0-tau, 0.f), q1s = fmaxf(p1-tau, 0.f);
    float q2s = fmaxf(p2-tau, 0.f), q3s = fmaxf(p3-tau, 0.f);
    int arg = 0; float best = q0s;
    if (q1s > best) { best = q1s; arg = 1; }
    if (q2s > best) { best = q2s; arg = 2; }
    if (q3s > best) { best = q3s; arg = 3; }
    amax[m0 + t] = arg;
    Wl[t][0] = q0s*inv; Wl[t][1] = q1s*inv; Wl[t][2] = q2s*inv; Wl[t][3] = q3s*inv;
  }
  __syncthreads();

  // per-subspace feature partials over this block's 64 tokens (x re-read ~L2)
  {
    int grp = t >> 7, dcol = t & 127;
    f32x4 a0 = {0,0,0,0};
#pragma unroll 8
    for (int tok = 0; tok < MT; ++tok) {
      f32x4 v = *(const f32x4*)&x[(size_t)(m0 + tok)*DD + dcol*4];
      a0 += v * Wl[tok][grp];
    }
    *(f32x4*)&partial[((size_t)blockIdx.x*4 + grp)*DD + dcol*4] = a0;
  }
}

// ---------------- finish: vote (recomputed per slice) + reduce -------------
__global__ __launch_bounds__(256) void finish_kernel(const int* __restrict__ amax,
    const float* __restrict__ partial, const int* __restrict__ mask,
    float* __restrict__ out) {
  __shared__ int cnt[4];
  __shared__ int vsh;
  int bb = blockIdx.x >> 3, slice = blockIdx.x & 7;
  int t = threadIdx.x;
  if (t < 4) cnt[t] = 0;
  __syncthreads();
  int m = mask[bb];
  int c0=0, c1=0, c2=0, c3=0;
  for (int n = t; n < NN; n += 256) {
    if (n < m) {
      int a = amax[bb*NN + n];
      c0 += (a==0); c1 += (a==1); c2 += (a==2); c3 += (a==3);
    }
  }
  atomicAdd(&cnt[0], c0); atomicAdd(&cnt[1], c1);
  atomicAdd(&cnt[2], c2); atomicAdd(&cnt[3], c3);
  __syncthreads();
  if (t == 0) {
    int arg = 0, best = cnt[0];
    if (cnt[1] > best) { best = cnt[1]; arg = 1; }
    if (cnt[2] > best) { best = cnt[2]; arg = 2; }
    if (cnt[3] > best) { best = cnt[3]; arg = 3; }
    vsh = arg;
  }
  __syncthreads();
  int v = vsh;
  if (t < 64) {
    int d = slice*64 + t;
    float f = 0.f;
#pragma unroll
    for (int c = 0; c < BPB; ++c)
      f += partial[(((size_t)(bb*BPB + c))*4 + v)*DD + d];
    out[bb*DD + d] = f;
  }
}

extern "C" void kernel_launch(void* const* d_in, const int* in_sizes, int n_in,
                              void* d_out, int out_size, void* d_ws, size_t ws_size,
                              hipStream_t stream) {
  const float* x    = (const float*)d_in[0];
  const int*   mask = (const int*)d_in[1];
  const float* sub  = (const float*)d_in[2];
  float* out = (float*)d_out;

  float* partial = (float*)d_ws;                         // 512*4*512 f32 = 4 MB
  int*   amax    = (int*)(partial + (size_t)NBLK*4*DD);  // 32768 ints
  unsigned short* subhi = (unsigned short*)(amax + NT);  // 131072 u16
  unsigned short* sublo = subhi + OUTC*DD;
  unsigned short* Ghi   = sublo + OUTC*DD;               // 16384 u16
  unsigned short* Glo   = Ghi + SS*RR*RR;

  // SCALE = 1.718*exp(-count/30000) - 0.718, count = B = 32
  double scale = 1.718 * exp(-((double)BB) / 30000.0) - 0.718;
  float inv_denom = (float)(1.0 / ((double)DD * scale));

  prep_kernel<<<128 + SS, 256, 0, stream>>>(sub, subhi, sublo, Ghi, Glo);
  fused_kernel<<<NBLK, 512, 0, stream>>>(x, subhi, sublo, Ghi, Glo, inv_denom, amax, partial);
  finish_kernel<<<BB*8, 256, 0, stream>>>(amax, partial, mask, out);
}

// Round 14
// 76.502 us; speedup vs baseline: 2.5351x; 1.0668x over previous
//
#include <hip/hip_runtime.h>
#include <math.h>

#define BB 32
#define NN 1024
#define DD 512
#define SS 4
#define RR 64
#define OUTC 256          // SS*RR
#define NT (BB*NN)        // 32768 tokens
#define MT 128            // tokens per fused block
#define NBLK (NT/MT)      // 256
#define BPB (NN/MT)       // blocks per batch = 8

// Per-K-step LDS buffer: A 128 rows x 128B f32 (granule-swizzled) = 16 KB,
// Bhi 256 cols x 64B = 16 KB, Blo 16 KB. Two buffers = 96 KB.
#define ABYTES 16384
#define BBYTES 16384
#define BUFBYTES (ABYTES + 2*BBYTES)

typedef float4 f4;
typedef float f32x4 __attribute__((ext_vector_type(4)));
typedef __bf16 bf16x8 __attribute__((ext_vector_type(8)));
typedef unsigned short u16x8 __attribute__((ext_vector_type(8)));
typedef const __attribute__((address_space(1))) void GVoid;
typedef __attribute__((address_space(3))) void LVoid;

union BF8 { u16x8 u; bf16x8 b; unsigned w[4]; };

__device__ __forceinline__ float hif(float f) {
  return __uint_as_float(__float_as_uint(f) & 0xffff0000u);
}
__device__ __forceinline__ unsigned short topu(float f) {
  return (unsigned short)(__float_as_uint(f) >> 16);
}
// identity-order pack: (bf16(e0), bf16(e1)) -> u32 (e0 in low half)
__device__ __forceinline__ unsigned pack2(float e0, float e1) {
  return __builtin_amdgcn_perm(__float_as_uint(e1), __float_as_uint(e0), 0x07060302u);
}

#define MFMA(a,b,c) __builtin_amdgcn_mfma_f32_16x16x32_bf16((a),(b),(c),0,0,0)

// ---------------- prep ------------------------------------------------------
// blocks 0..63: sub -> bf16 hi/lo planes in [kc][col][64B, granule-swizzled]
// blocks 64..67: Gram G_s = S_s S_s^T -> bf16 hi/lo (linear layout)
__global__ __launch_bounds__(256) void prep_kernel(const float* __restrict__ sub,
    unsigned short* __restrict__ subhiK, unsigned short* __restrict__ subloK,
    unsigned short* __restrict__ Ghi, unsigned short* __restrict__ Glo) {
  int t = threadIdx.x, blk = blockIdx.x;
  if (blk < 64) {
    int idx = blk*256 + t;            // 16384 granule tasks
    int col = idx >> 6;               // 0..255
    int rem = idx & 63;
    int kc = rem >> 2, g = rem & 3;
    const float* p = &sub[(size_t)col*DD + kc*32 + g*8];
    f4 v0 = *(const f4*)p;
    f4 v1 = *(const f4*)(p + 4);
    BF8 hi, lo;
    hi.w[0] = pack2(v0.x, v0.y); hi.w[1] = pack2(v0.z, v0.w);
    hi.w[2] = pack2(v1.x, v1.y); hi.w[3] = pack2(v1.z, v1.w);
    lo.w[0] = pack2(v0.x - hif(v0.x), v0.y - hif(v0.y));
    lo.w[1] = pack2(v0.z - hif(v0.z), v0.w - hif(v0.w));
    lo.w[2] = pack2(v1.x - hif(v1.x), v1.y - hif(v1.y));
    lo.w[3] = pack2(v1.z - hif(v1.z), v1.w - hif(v1.w));
    int slot = g ^ ((col >> 1) & 3);
    size_t off = (size_t)kc*(OUTC*32) + (size_t)col*32 + slot*8;
    *(u16x8*)&subhiK[off] = hi.u;
    *(u16x8*)&subloK[off] = lo.u;
    return;
  }
  // Gram
  __shared__ __align__(16) float Sl[64][36];
  int s = blk - 64;
  int lane = t & 63, w = t >> 6, l15 = lane & 15, l4 = lane >> 4;
  int row = t >> 2, seg = t & 3;
  f4 r0, r1;
  f32x4 acc[4] = {{0,0,0,0},{0,0,0,0},{0,0,0,0},{0,0,0,0}};
  {
    const float* p = &sub[(size_t)(s*RR + row)*DD + seg*8];
    r0 = *(const f4*)p; r1 = *(const f4*)(p+4);
  }
#pragma unroll 1
  for (int kc = 0; kc < 16; ++kc) {
    __syncthreads();
    *(f4*)&Sl[row][seg*8]   = r0;
    *(f4*)&Sl[row][seg*8+4] = r1;
    __syncthreads();
    if (kc < 15) {
      const float* p = &sub[(size_t)(s*RR + row)*DD + (kc+1)*32 + seg*8];
      r0 = *(const f4*)p; r1 = *(const f4*)(p+4);
    }
    BF8 ah, al;
    {
      int ra = w*16 + l15;
      f32x4 v0 = *(const f32x4*)&Sl[ra][l4*8];
      f32x4 v1 = *(const f32x4*)&Sl[ra][l4*8+4];
      float ff[8] = {v0[0],v0[1],v0[2],v0[3],v1[0],v1[1],v1[2],v1[3]};
#pragma unroll
      for (int e = 0; e < 8; ++e) { ah.u[e] = topu(ff[e]); al.u[e] = topu(ff[e]-hif(ff[e])); }
    }
#pragma unroll
    for (int j = 0; j < 4; ++j) {
      BF8 bh, bl;
      int rb = j*16 + l15;
      f32x4 v0 = *(const f32x4*)&Sl[rb][l4*8];
      f32x4 v1 = *(const f32x4*)&Sl[rb][l4*8+4];
      float ff[8] = {v0[0],v0[1],v0[2],v0[3],v1[0],v1[1],v1[2],v1[3]};
#pragma unroll
      for (int e = 0; e < 8; ++e) { bh.u[e] = topu(ff[e]); bl.u[e] = topu(ff[e]-hif(ff[e])); }
      acc[j] = MFMA(ah.b, bh.b, acc[j]);
      acc[j] = MFMA(ah.b, bl.b, acc[j]);
      acc[j] = MFMA(al.b, bh.b, acc[j]);
    }
  }
#pragma unroll
  for (int j = 0; j < 4; ++j)
#pragma unroll
    for (int r = 0; r < 4; ++r) {
      int grow = w*16 + l4*4 + r, gcol = j*16 + l15;
      float v = acc[j][r];
      Ghi[((size_t)s*RR + grow)*RR + gcol] = topu(v);
      Glo[((size_t)s*RR + grow)*RR + gcol] = topu(v - hif(v));
    }
}

// ---------------- fused: 128x256 tile, m97-style gload_lds staging ----------
// 8 waves = 2 mh x 4 sl. Wave (mh,sl): rows mh*64+0..63, subspace sl (64 cols).
// acc 4x4 f32x4 per wave. A f32 via gload_lds (per-lane swizzled source);
// B bf16 hi/lo via gload_lds (pre-swizzled global). Counted vmcnt(6).
__global__ __launch_bounds__(512, 2) void fused_kernel(
    const float* __restrict__ x,
    const unsigned short* __restrict__ subhiK, const unsigned short* __restrict__ subloK,
    const unsigned short* __restrict__ Ghi, const unsigned short* __restrict__ Glo,
    float inv_denom, int* __restrict__ amax, float* __restrict__ partial) {
  __shared__ __align__(16) char smem[2*BUFBYTES];   // 96 KB stage; reused as ysc
  __shared__ float ssqarr[MT];
  __shared__ float prq2[MT][4];
  __shared__ float Wl[MT][4];

  int t = threadIdx.x;
  int lane = t & 63, w = t >> 6;
  int sl = w & 3, mh = w >> 2;
  int l15 = lane & 15, l4 = lane >> 4;
  int m0 = blockIdx.x * MT;

  f32x4 acc[4][4] = {};
  float ssq4[4] = {0.f, 0.f, 0.f, 0.f};

  auto stageA = [&](int buf, int kc) {
#pragma unroll
    for (int jj = 0; jj < 2; ++jj) {
      int j = w*2 + jj;                       // 16 instrs: rows j*8..j*8+7
      int row = j*8 + (lane >> 3);
      int g = lane & 7;
      int gs = g ^ (row & 7);                 // swizzled source granule
      const float* src = x + (size_t)(m0 + row)*DD + kc*32 + gs*4;
      __builtin_amdgcn_global_load_lds((GVoid*)src,
          (LVoid*)(smem + buf*BUFBYTES + j*1024 + lane*16), 16, 0, 0);
    }
  };
  auto stageB = [&](int buf, int kc) {
#pragma unroll
    for (int jj = 0; jj < 4; ++jj) {
      int jb = w*4 + jj;                      // 32 instrs
      int plane = jb >> 4;                    // 0 hi, 1 lo
      int idx = jb & 15;                      // 16-col group
      const unsigned short* sp = (plane ? subloK : subhiK)
          + (size_t)kc*(OUTC*32) + (size_t)idx*512;
      __builtin_amdgcn_global_load_lds((GVoid*)((const char*)sp + lane*16),
          (LVoid*)(smem + buf*BUFBYTES + ABYTES + plane*BBYTES + idx*1024 + lane*16),
          16, 0, 0);
    }
  };
  auto kstep = [&](int buf) {
    const char* Ab = smem + buf*BUFBYTES;
    const char* Bh = Ab + ABYTES;
    const char* Bl = Bh + BBYTES;
    BF8 bh[4], bl[4];
#pragma unroll
    for (int nf = 0; nf < 4; ++nf) {
      int col = sl*64 + nf*16 + l15;
      int slot = l4 ^ ((col >> 1) & 3);
      bh[nf].u = *(const u16x8*)(Bh + col*64 + slot*16);
      bl[nf].u = *(const u16x8*)(Bl + col*64 + slot*16);
    }
#pragma unroll
    for (int mf = 0; mf < 4; ++mf) {
      int row = mh*64 + mf*16 + l15;
      int s0 = (2*l4) ^ (row & 7);
      int s1 = s0 ^ 1;
      f32x4 v0 = *(const f32x4*)(Ab + row*128 + s0*16);   // k l4*8..+3
      f32x4 v1 = *(const f32x4*)(Ab + row*128 + s1*16);   // k l4*8+4..+7
      float f0=v0[0], f1=v0[1], f2=v0[2], f3=v0[3];
      float g4=v1[0], g5=v1[1], g6=v1[2], g7=v1[3];
      if (sl == 0)
        ssq4[mf] += f0*f0+f1*f1+f2*f2+f3*f3+g4*g4+g5*g5+g6*g6+g7*g7;
      BF8 ah, al;
      ah.w[0] = pack2(f0,f1); ah.w[1] = pack2(f2,f3);
      ah.w[2] = pack2(g4,g5); ah.w[3] = pack2(g6,g7);
      al.w[0] = pack2(f0-hif(f0), f1-hif(f1));
      al.w[1] = pack2(f2-hif(f2), f3-hif(f3));
      al.w[2] = pack2(g4-hif(g4), g5-hif(g5));
      al.w[3] = pack2(g6-hif(g6), g7-hif(g7));
#pragma unroll
      for (int nf = 0; nf < 4; ++nf) {
        acc[mf][nf] = MFMA(ah.b, bh[nf].b, acc[mf][nf]);
        acc[mf][nf] = MFMA(ah.b, bl[nf].b, acc[mf][nf]);
        acc[mf][nf] = MFMA(al.b, bh[nf].b, acc[mf][nf]);
      }
    }
  };

  // prologue
  stageA(0, 0); stageB(0, 0);
  asm volatile("s_waitcnt vmcnt(0)" ::: "memory");
  __builtin_amdgcn_s_barrier();
  __builtin_amdgcn_sched_barrier(0);

#pragma unroll 2
  for (int kc = 0; kc < 16; ++kc) {
    int buf = kc & 1;
    if (kc < 15) {
      stageA(buf^1, kc+1); stageB(buf^1, kc+1);
      asm volatile("s_waitcnt vmcnt(6)" ::: "memory");  // stage(kc) retired; kc+1 in flight
    } else {
      asm volatile("s_waitcnt vmcnt(0)" ::: "memory");
    }
    __builtin_amdgcn_s_barrier();       // stage(kc) visible to all waves
    __builtin_amdgcn_sched_barrier(0);
    kstep(buf);
    __builtin_amdgcn_sched_barrier(0);  // keep ds_reads above the barrier
    __builtin_amdgcn_s_barrier();       // reads of buf done before restage
  }

  // ssq reduce (sl==0 waves cover all 128 rows)
  if (sl == 0) {
#pragma unroll
    for (int mf = 0; mf < 4; ++mf) {
      float v = ssq4[mf];
      v += __shfl_xor(v, 16); v += __shfl_xor(v, 32);
      if (l4 == 0) ssqarr[mh*64 + mf*16 + l15] = v;
    }
  }

  // G fragments (L2-resident, linear layout)
  BF8 gh[2][4], gl2[2][4];
#pragma unroll
  for (int kf = 0; kf < 2; ++kf)
#pragma unroll
    for (int nf = 0; nf < 4; ++nf) {
      size_t off = (size_t)(sl*RR + nf*16 + l15)*RR + kf*32 + l4*8;
      gh[kf][nf].u  = *(const u16x8*)&Ghi[off];
      gl2[kf][nf].u = *(const u16x8*)&Glo[off];
    }
  __syncthreads();   // stage area becomes per-wave ysc scratch

  float* ysc = (float*)smem + (size_t)w*1088;   // per-wave private 16x68 f32
#pragma unroll
  for (int h = 0; h < 4; ++h) {
#pragma unroll
    for (int nf = 0; nf < 4; ++nf)
#pragma unroll
      for (int r = 0; r < 4; ++r)
        ysc[(l4*4 + r)*68 + nf*16 + l15] = acc[h][nf][r];
    // wave-private: no block barrier needed; compiler orders ds ops
    BF8 yh[2], yl[2];
#pragma unroll
    for (int kf = 0; kf < 2; ++kf) {
      int base = l15*68 + kf*32 + l4*8;
      f32x4 v0 = *(const f32x4*)&ysc[base];
      f32x4 v1 = *(const f32x4*)&ysc[base+4];
      float ff[8] = {v0[0],v0[1],v0[2],v0[3],v1[0],v1[1],v1[2],v1[3]};
#pragma unroll
      for (int e = 0; e < 8; ++e) {
        yh[kf].u[e] = topu(ff[e]);
        yl[kf].u[e] = topu(ff[e] - hif(ff[e]));
      }
    }
    f32x4 z[4] = {};
#pragma unroll
    for (int nf = 0; nf < 4; ++nf)
#pragma unroll
      for (int kf = 0; kf < 2; ++kf) {
        z[nf] = MFMA(yh[kf].b, gh[kf][nf].b,  z[nf]);
        z[nf] = MFMA(yh[kf].b, gl2[kf][nf].b, z[nf]);
        z[nf] = MFMA(yl[kf].b, gh[kf][nf].b,  z[nf]);
      }
#pragma unroll
    for (int r = 0; r < 4; ++r) {
      float qp = z[0][r]*acc[h][0][r] + z[1][r]*acc[h][1][r]
               + z[2][r]*acc[h][2][r] + z[3][r]*acc[h][3][r];
      qp += __shfl_xor(qp, 1); qp += __shfl_xor(qp, 2);
      qp += __shfl_xor(qp, 4); qp += __shfl_xor(qp, 8);
      if (l15 == 0) prq2[mh*64 + h*16 + l4*4 + r][sl] = qp;
    }
  }
  __syncthreads();

  if (t < MT) {
    float ss = ssqarr[t];
    float inv = 1.f / fmaxf(sqrtf(ss), 1e-12f);
    float p0 = sqrtf(fmaxf(prq2[t][0], 0.f)) * inv * inv_denom;
    float p1 = sqrtf(fmaxf(prq2[t][1], 0.f)) * inv * inv_denom;
    float p2 = sqrtf(fmaxf(prq2[t][2], 0.f)) * inv * inv_denom;
    float p3 = sqrtf(fmaxf(prq2[t][3], 0.f)) * inv * inv_denom;
    float a0=p0, a1=p1, a2=p2, a3=p3, hi, lo;
    hi = fmaxf(a0,a1); lo = fminf(a0,a1); a0=hi; a1=lo;
    hi = fmaxf(a2,a3); lo = fminf(a2,a3); a2=hi; a3=lo;
    hi = fmaxf(a0,a2); lo = fminf(a0,a2); a0=hi; a2=lo;
    hi = fmaxf(a1,a3); lo = fminf(a1,a3); a1=hi; a3=lo;
    hi = fmaxf(a1,a2); lo = fminf(a1,a2); a1=hi; a2=lo;
    float c2 = a0+a1, c3 = c2+a2, c4s = c3+a3;
    int ksup = 1 + (2.f*a1 > c2-1.f) + (3.f*a2 > c3-1.f) + (4.f*a3 > c4s-1.f);
    float csel = (ksup==1) ? a0 : (ksup==2) ? c2 : (ksup==3) ? c3 : c4s;
    float tau = (csel - 1.f) / (float)ksup;
    float q0 = fmaxf(p0-tau, 0.f), q1 = fmaxf(p1-tau, 0.f);
    float q2 = fmaxf(p2-tau, 0.f), q3 = fmaxf(p3-tau, 0.f);
    int arg = 0; float best = q0;
    if (q1 > best) { best = q1; arg = 1; }
    if (q2 > best) { best = q2; arg = 2; }
    if (q3 > best) { best = q3; arg = 3; }
    amax[m0 + t] = arg;
    Wl[t][0] = q0*inv; Wl[t][1] = q1*inv; Wl[t][2] = q2*inv; Wl[t][3] = q3*inv;
  }
  __syncthreads();

  // per-subspace feature partials over this block's 128 tokens (x ~L2/L3)
  {
    int grp = t >> 7, dcol = t & 127;
    f32x4 a0 = {0,0,0,0};
#pragma unroll 8
    for (int tok = 0; tok < MT; ++tok) {
      f32x4 v = *(const f32x4*)&x[(size_t)(m0 + tok)*DD + dcol*4];
      a0 += v * Wl[tok][grp];
    }
    *(f32x4*)&partial[((size_t)blockIdx.x*4 + grp)*DD + dcol*4] = a0;
  }
}

// ---------------- finish: vote (recomputed per slice) + reduce -------------
__global__ __launch_bounds__(256) void finish_kernel(const int* __restrict__ amax,
    const float* __restrict__ partial, const int* __restrict__ mask,
    float* __restrict__ out) {
  __shared__ int cnt[4];
  __shared__ int vsh;
  int bb = blockIdx.x >> 3, slice = blockIdx.x & 7;
  int t = threadIdx.x;
  if (t < 4) cnt[t] = 0;
  __syncthreads();
  int m = mask[bb];
  int c0=0, c1=0, c2=0, c3=0;
  for (int n = t; n < NN; n += 256) {
    if (n < m) {
      int a = amax[bb*NN + n];
      c0 += (a==0); c1 += (a==1); c2 += (a==2); c3 += (a==3);
    }
  }
  atomicAdd(&cnt[0], c0); atomicAdd(&cnt[1], c1);
  atomicAdd(&cnt[2], c2); atomicAdd(&cnt[3], c3);
  __syncthreads();
  if (t == 0) {
    int arg = 0, best = cnt[0];
    if (cnt[1] > best) { best = cnt[1]; arg = 1; }
    if (cnt[2] > best) { best = cnt[2]; arg = 2; }
    if (cnt[3] > best) { best = cnt[3]; arg = 3; }
    vsh = arg;
  }
  __syncthreads();
  int v = vsh;
  if (t < 64) {
    int d = slice*64 + t;
    float f = 0.f;
#pragma unroll
    for (int c = 0; c < BPB; ++c)
      f += partial[(((size_t)(bb*BPB + c))*4 + v)*DD + d];
    out[bb*DD + d] = f;
  }
}

extern "C" void kernel_launch(void* const* d_in, const int* in_sizes, int n_in,
                              void* d_out, int out_size, void* d_ws, size_t ws_size,
                              hipStream_t stream) {
  const float* x    = (const float*)d_in[0];
  const int*   mask = (const int*)d_in[1];
  const float* sub  = (const float*)d_in[2];
  float* out = (float*)d_out;

  float* partial = (float*)d_ws;                          // 256*4*512 f32 = 2 MB
  int*   amax    = (int*)(partial + (size_t)NBLK*4*DD);   // 32768 ints
  unsigned short* subhiK = (unsigned short*)(amax + NT);  // 131072 u16
  unsigned short* subloK = subhiK + OUTC*DD;
  unsigned short* Ghi    = subloK + OUTC*DD;              // 16384 u16
  unsigned short* Glo    = Ghi + SS*RR*RR;

  // SCALE = 1.718*exp(-count/30000) - 0.718, count = B = 32
  double scale = 1.718 * exp(-((double)BB) / 30000.0) - 0.718;
  float inv_denom = (float)(1.0 / ((double)DD * scale));

  prep_kernel<<<64 + SS, 256, 0, stream>>>(sub, subhiK, subloK, Ghi, Glo);
  fused_kernel<<<NBLK, 512, 0, stream>>>(x, subhiK, subloK, Ghi, Glo, inv_denom, amax, partial);
  finish_kernel<<<BB*8, 256, 0, stream>>>(amax, partial, mask, out);
}